// Round 9
// baseline (959.322 us; speedup 1.0000x reference)
//
#include <hip/hip_runtime.h>
#include <hip/hip_bf16.h>

#define KD 6
#define DD 3
#define CO 32
#define CI 32
#define KC (KD * CO)   // 192
#define QP (KC / 2)    // 96 uints (bf16 pairs) per xg row

__device__ __forceinline__ uint pack_bf16(float a, float b) {
    uint lo = (uint)__bfloat16_as_ushort(__float2bfloat16(a));
    uint hi = (uint)__bfloat16_as_ushort(__float2bfloat16(b));
    return lo | (hi << 16);
}
__device__ __forceinline__ float bf_lo(uint u) { return __uint_as_float(u << 16); }
__device__ __forceinline__ float bf_hi(uint u) { return __uint_as_float(u & 0xffff0000u); }

// ---------------- kernel 0: per-edge Gaussian weights -> W[E] (uint4: 6 bf16 + pad) ----
__global__ void gauss_kernel(const float* __restrict__ pseudo, const float* __restrict__ mu,
                             const float* __restrict__ sigma, uint4* __restrict__ W, int E) {
    float m[KD][DD], iv[KD][DD];
#pragma unroll
    for (int k = 0; k < KD; ++k)
#pragma unroll
        for (int d = 0; d < DD; ++d) {
            m[k][d] = mu[k * DD + d];
            float s = sigma[k * DD + d];
            iv[k][d] = -0.5f / (1e-15f + s * s);
        }
    for (int e = blockIdx.x * blockDim.x + threadIdx.x; e < E;
         e += gridDim.x * blockDim.x) {
        float p0 = pseudo[3 * e], p1 = pseudo[3 * e + 1], p2 = pseudo[3 * e + 2];
        float w[KD];
#pragma unroll
        for (int k = 0; k < KD; ++k) {
            float d0 = p0 - m[k][0], d1 = p1 - m[k][1], d2 = p2 - m[k][2];
            w[k] = __expf(d0 * d0 * iv[k][0] + d1 * d1 * iv[k][1] + d2 * d2 * iv[k][2]);
        }
        W[e] = make_uint4(pack_bf16(w[0], w[1]), pack_bf16(w[2], w[3]),
                          pack_bf16(w[4], w[5]), 0u);
    }
}

// ---------------- kernel 1: xg = x @ g -> bf16 ws [N, 192] ----------------
// Thread = 4 rows x 4 cols; g from LDS via ds_read_b128, amortized over 4 rows.
__global__ void xg_kernel(const float* __restrict__ x, const float* __restrict__ g,
                          uint* __restrict__ xg, int N) {
    __shared__ float gs[CI * KC];  // 24 KiB
    for (int i = threadIdx.x; i < CI * KC; i += blockDim.x) gs[i] = g[i];
    __syncthreads();
    const int NB = (N + 3) >> 2;
    const int total = NB * 48;  // 48 col-quads per row-block
    for (int idx = blockIdx.x * blockDim.x + threadIdx.x; idx < total;
         idx += gridDim.x * blockDim.x) {
        const int b = idx / 48;
        const int t = idx - b * 48;   // cols 4t..4t+3
        const int n0 = b * 4;
        const float* xr[4];
#pragma unroll
        for (int r = 0; r < 4; ++r) {
            int n = n0 + r; if (n > N - 1) n = N - 1;   // clamp tail loads
            xr[r] = x + (size_t)n * CI;
        }
        float acc[4][4];
#pragma unroll
        for (int r = 0; r < 4; ++r)
#pragma unroll
            for (int j = 0; j < 4; ++j) acc[r][j] = 0.f;
#pragma unroll
        for (int c = 0; c < CI; ++c) {
            const float4 gv = *(const float4*)&gs[c * KC + 4 * t];
#pragma unroll
            for (int r = 0; r < 4; ++r) {
                float xc = xr[r][c];
                acc[r][0] = fmaf(xc, gv.x, acc[r][0]);
                acc[r][1] = fmaf(xc, gv.y, acc[r][1]);
                acc[r][2] = fmaf(xc, gv.z, acc[r][2]);
                acc[r][3] = fmaf(xc, gv.w, acc[r][3]);
            }
        }
#pragma unroll
        for (int r = 0; r < 4; ++r) {
            int n = n0 + r;
            if (n < N) {
                uint2 pk = make_uint2(pack_bf16(acc[r][0], acc[r][1]),
                                      pack_bf16(acc[r][2], acc[r][3]));
                *(uint2*)(xg + (size_t)n * QP + 2 * t) = pk;
            }
        }
    }
}

// ---------------- kernel 2: per-edge message + atomic scatter ----------------
// 32 lanes/edge. Lane l: pair p=l&15 (channels 2p,2p+1), kbase=l>>4.
// Loads uints j=l,l+32,l+64 of the 96-uint xg row (k = kbase+{0,2,4}).
// shfl_xor(16) merges complementary k-sets; 1 atomic per lane.
__global__ void edge_kernel(const int* __restrict__ ei, const uint4* __restrict__ W,
                            const uint* __restrict__ xg,
                            float* __restrict__ agg, float* __restrict__ cnt, int E) {
    const int l = threadIdx.x & 31;
    const int kbase = l >> 4;       // 0 or 1
    const int p = l & 15;           // channel pair
    const int gpb = blockDim.x >> 5;
    const int e0 = blockIdx.x * gpb + (threadIdx.x >> 5);
    const int estride = gridDim.x * gpb;
    for (int e = e0; e < E; e += estride) {
        const int src = ei[e];
        const int dst = ei[E + e];
        const uint4 wv = W[e];
        // select this lane's 3 weights: w[kbase], w[kbase+2], w[kbase+4]
        float wa = __uint_as_float((kbase ? (wv.x >> 16) : (wv.x & 0xffffu)) << 16);
        float wb = __uint_as_float((kbase ? (wv.y >> 16) : (wv.y & 0xffffu)) << 16);
        float wc = __uint_as_float((kbase ? (wv.z >> 16) : (wv.z & 0xffffu)) << 16);
        const uint* xr = xg + (size_t)src * QP;
        const uint u0 = xr[l];
        const uint u1 = xr[l + 32];
        const uint u2 = xr[l + 64];
        float s0 = wa * bf_lo(u0), s1 = wa * bf_hi(u0);
        s0 = fmaf(wb, bf_lo(u1), s0); s1 = fmaf(wb, bf_hi(u1), s1);
        s0 = fmaf(wc, bf_lo(u2), s0); s1 = fmaf(wc, bf_hi(u2), s1);
        s0 += __shfl_xor(s0, 16);   // merge complementary kbase (same pair p)
        s1 += __shfl_xor(s1, 16);
        const float val = kbase ? s1 : s0;
        const int ch = 2 * p + kbase;
        atomicAdd(&agg[(size_t)dst * CO + ch], val);
        if (l == 0) atomicAdd(&cnt[dst], 1.0f);
    }
}

// ---------------- kernel 3: out = agg/max(cnt,1) + x@root + bias ----------------
__global__ void out_kernel(const float* __restrict__ x, const float* __restrict__ root,
                           const float* __restrict__ bias, const float* __restrict__ cnt,
                           float* __restrict__ out, int N) {
    __shared__ float rs[CI * CO];  // 4 KiB
    __shared__ float bs[CO];
    for (int i = threadIdx.x; i < CI * CO; i += blockDim.x) rs[i] = root[i];
    if (threadIdx.x < CO) bs[threadIdx.x] = bias[threadIdx.x];
    __syncthreads();
    const int total = N * 8;  // channel quads
    for (int idx = blockIdx.x * blockDim.x + threadIdx.x; idx < total;
         idx += gridDim.x * blockDim.x) {
        const int n = idx >> 3;
        const int t = idx & 7;     // channels 4t..4t+3
        const float* xr = x + (size_t)n * CI;
        float a0 = 0.f, a1 = 0.f, a2 = 0.f, a3 = 0.f;
#pragma unroll
        for (int c = 0; c < CI; ++c) {
            const float4 rv = *(const float4*)&rs[c * CO + 4 * t];
            float xc = xr[c];
            a0 = fmaf(xc, rv.x, a0);
            a1 = fmaf(xc, rv.y, a1);
            a2 = fmaf(xc, rv.z, a2);
            a3 = fmaf(xc, rv.w, a3);
        }
        const float inv = 1.0f / fmaxf(cnt[n], 1.0f);
        float4 o = *(float4*)&out[(size_t)n * CO + 4 * t];
        const float4 bv = *(const float4*)&bs[4 * t];
        o.x = o.x * inv + a0 + bv.x;
        o.y = o.y * inv + a1 + bv.y;
        o.z = o.z * inv + a2 + bv.z;
        o.w = o.w * inv + a3 + bv.w;
        *(float4*)&out[(size_t)n * CO + 4 * t] = o;
    }
}

extern "C" void kernel_launch(void* const* d_in, const int* in_sizes, int n_in,
                              void* d_out, int out_size, void* d_ws, size_t ws_size,
                              hipStream_t stream) {
    const float* x      = (const float*)d_in[0];
    const int*   ei     = (const int*)d_in[1];
    const float* pseudo = (const float*)d_in[2];
    const float* g      = (const float*)d_in[3];
    const float* mu     = (const float*)d_in[4];
    const float* sigma  = (const float*)d_in[5];
    const float* root   = (const float*)d_in[6];
    const float* bias   = (const float*)d_in[7];
    float* out = (float*)d_out;

    const int N = in_sizes[0] / CI;
    const int E = in_sizes[1] / 2;

    uint*  xg = (uint*)d_ws;                          // N*96 uints = 62.9 MB
    uint4* W  = (uint4*)(xg + (size_t)N * QP);        // E*16B = 18.4 MB (16B-aligned)
    float* cnt = (float*)(W + E);                     // N floats

    hipMemsetAsync(d_out, 0, (size_t)out_size * sizeof(float), stream);
    hipMemsetAsync(cnt, 0, (size_t)N * sizeof(float), stream);

    const int blk = 256;

    gauss_kernel<<<(E + blk - 1) / blk, blk, 0, stream>>>(pseudo, mu, sigma, W, E);

    xg_kernel<<<2048, blk, 0, stream>>>(x, g, xg, N);

    const int gpb = blk / 32;
    int grid2 = (E + gpb - 1) / gpb;
    if (grid2 > 16384) grid2 = 16384;
    edge_kernel<<<grid2, blk, 0, stream>>>(ei, W, xg, out, cnt, E);

    int grid3 = (N * 8 + blk - 1) / blk;
    if (grid3 > 4096) grid3 = 4096;
    out_kernel<<<grid3, blk, 0, stream>>>(x, root, bias, cnt, out, N);
}

// Round 10
// 355.100 us; speedup vs baseline: 2.7016x; 2.7016x over previous
//
#include <hip/hip_runtime.h>
#include <hip/hip_bf16.h>

#define KD 6
#define DD 3
#define CO 32
#define CI 32
#define KC (KD * CO)   // 192
#define QP (KC / 2)    // 96 uints (bf16 pairs) per xg row

__device__ __forceinline__ uint pack_bf16(float a, float b) {
    uint lo = (uint)__bfloat16_as_ushort(__float2bfloat16(a));
    uint hi = (uint)__bfloat16_as_ushort(__float2bfloat16(b));
    return lo | (hi << 16);
}
__device__ __forceinline__ float bf_lo(uint u) { return __uint_as_float(u << 16); }
__device__ __forceinline__ float bf_hi(uint u) { return __uint_as_float(u & 0xffff0000u); }

// ---------------- kernel 0: per-edge Gaussian weights -> W[E] (uint4: 6 bf16 + pad) ----
__global__ void gauss_kernel(const float* __restrict__ pseudo, const float* __restrict__ mu,
                             const float* __restrict__ sigma, uint4* __restrict__ W, int E) {
    float m[KD][DD], iv[KD][DD];
#pragma unroll
    for (int k = 0; k < KD; ++k)
#pragma unroll
        for (int d = 0; d < DD; ++d) {
            m[k][d] = mu[k * DD + d];
            float s = sigma[k * DD + d];
            iv[k][d] = -0.5f / (1e-15f + s * s);
        }
    for (int e = blockIdx.x * blockDim.x + threadIdx.x; e < E;
         e += gridDim.x * blockDim.x) {
        float p0 = pseudo[3 * e], p1 = pseudo[3 * e + 1], p2 = pseudo[3 * e + 2];
        float w[KD];
#pragma unroll
        for (int k = 0; k < KD; ++k) {
            float d0 = p0 - m[k][0], d1 = p1 - m[k][1], d2 = p2 - m[k][2];
            w[k] = __expf(d0 * d0 * iv[k][0] + d1 * d1 * iv[k][1] + d2 * d2 * iv[k][2]);
        }
        W[e] = make_uint4(pack_bf16(w[0], w[1]), pack_bf16(w[2], w[3]),
                          pack_bf16(w[4], w[5]), 0u);
    }
}

// ---------------- kernel 1: xg = x @ g -> bf16 ws [N, 192] ----------------
// Low-pressure tile: thread = 2 rows x 4 cols. Per c-step(4): 2 float4 x-loads,
// 4 ds_read_b128 g-loads, 32 FMA. launch_bounds caps occupancy demand so the
// compiler gets 128 VGPRs -> no scratch spill (rounds 5/9 pathology: VGPR=64
// cap forced GB-scale spill traffic, hbm 2.9-4.4 GB, VALUBusy <4%).
__global__ __launch_bounds__(256, 4)
void xg_kernel(const float* __restrict__ x, const float* __restrict__ g,
               uint* __restrict__ xg, int N) {
    __shared__ float gs[CI * KC];  // 24 KiB
    for (int i = threadIdx.x; i < CI * KC; i += blockDim.x) gs[i] = g[i];
    __syncthreads();
    const int NP = (N + 1) >> 1;        // row pairs (N even in practice)
    const int total = NP * 48;          // 48 col-quads per row pair
    for (int idx = blockIdx.x * blockDim.x + threadIdx.x; idx < total;
         idx += gridDim.x * blockDim.x) {
        const int rp = idx / 48;
        const int t = idx - rp * 48;    // cols 4t..4t+3
        const int n0 = rp * 2;
        const int n1 = (n0 + 1 < N) ? (n0 + 1) : n0;
        const float* xr0 = x + (size_t)n0 * CI;
        const float* xr1 = x + (size_t)n1 * CI;
        float a00 = 0.f, a01 = 0.f, a02 = 0.f, a03 = 0.f;
        float a10 = 0.f, a11 = 0.f, a12 = 0.f, a13 = 0.f;
#pragma unroll 2
        for (int c = 0; c < CI; c += 4) {
            const float4 xv0 = *(const float4*)&xr0[c];
            const float4 xv1 = *(const float4*)&xr1[c];
            const float4 g0 = *(const float4*)&gs[(c + 0) * KC + 4 * t];
            const float4 g1 = *(const float4*)&gs[(c + 1) * KC + 4 * t];
            const float4 g2 = *(const float4*)&gs[(c + 2) * KC + 4 * t];
            const float4 g3 = *(const float4*)&gs[(c + 3) * KC + 4 * t];
            a00 = fmaf(xv0.x, g0.x, a00); a01 = fmaf(xv0.x, g0.y, a01);
            a02 = fmaf(xv0.x, g0.z, a02); a03 = fmaf(xv0.x, g0.w, a03);
            a10 = fmaf(xv1.x, g0.x, a10); a11 = fmaf(xv1.x, g0.y, a11);
            a12 = fmaf(xv1.x, g0.z, a12); a13 = fmaf(xv1.x, g0.w, a13);
            a00 = fmaf(xv0.y, g1.x, a00); a01 = fmaf(xv0.y, g1.y, a01);
            a02 = fmaf(xv0.y, g1.z, a02); a03 = fmaf(xv0.y, g1.w, a03);
            a10 = fmaf(xv1.y, g1.x, a10); a11 = fmaf(xv1.y, g1.y, a11);
            a12 = fmaf(xv1.y, g1.z, a12); a13 = fmaf(xv1.y, g1.w, a13);
            a00 = fmaf(xv0.z, g2.x, a00); a01 = fmaf(xv0.z, g2.y, a01);
            a02 = fmaf(xv0.z, g2.z, a02); a03 = fmaf(xv0.z, g2.w, a03);
            a10 = fmaf(xv1.z, g2.x, a10); a11 = fmaf(xv1.z, g2.y, a11);
            a12 = fmaf(xv1.z, g2.z, a12); a13 = fmaf(xv1.z, g2.w, a13);
            a00 = fmaf(xv0.w, g3.x, a00); a01 = fmaf(xv0.w, g3.y, a01);
            a02 = fmaf(xv0.w, g3.z, a02); a03 = fmaf(xv0.w, g3.w, a03);
            a10 = fmaf(xv1.w, g3.x, a10); a11 = fmaf(xv1.w, g3.y, a11);
            a12 = fmaf(xv1.w, g3.z, a12); a13 = fmaf(xv1.w, g3.w, a13);
        }
        uint2 pk0 = make_uint2(pack_bf16(a00, a01), pack_bf16(a02, a03));
        *(uint2*)(xg + (size_t)n0 * QP + 2 * t) = pk0;
        if (n0 + 1 < N) {
            uint2 pk1 = make_uint2(pack_bf16(a10, a11), pack_bf16(a12, a13));
            *(uint2*)(xg + (size_t)(n0 + 1) * QP + 2 * t) = pk1;
        }
    }
}

// ---------------- kernel 2: per-edge message + atomic scatter ----------------
// 32 lanes/edge. Lane l: pair p=l&15 (channels 2p,2p+1), kbase=l>>4.
// Loads uints j=l,l+32,l+64 of the 96-uint xg row (k = kbase+{0,2,4}).
// shfl_xor(16) merges complementary k-sets; 1 atomic per lane.
__global__ void edge_kernel(const int* __restrict__ ei, const uint4* __restrict__ W,
                            const uint* __restrict__ xg,
                            float* __restrict__ agg, float* __restrict__ cnt, int E) {
    const int l = threadIdx.x & 31;
    const int kbase = l >> 4;       // 0 or 1
    const int p = l & 15;           // channel pair
    const int gpb = blockDim.x >> 5;
    const int e0 = blockIdx.x * gpb + (threadIdx.x >> 5);
    const int estride = gridDim.x * gpb;
    for (int e = e0; e < E; e += estride) {
        const int src = ei[e];
        const int dst = ei[E + e];
        const uint4 wv = W[e];
        // select this lane's 3 weights: w[kbase], w[kbase+2], w[kbase+4]
        float wa = __uint_as_float((kbase ? (wv.x >> 16) : (wv.x & 0xffffu)) << 16);
        float wb = __uint_as_float((kbase ? (wv.y >> 16) : (wv.y & 0xffffu)) << 16);
        float wc = __uint_as_float((kbase ? (wv.z >> 16) : (wv.z & 0xffffu)) << 16);
        const uint* xr = xg + (size_t)src * QP;
        const uint u0 = xr[l];
        const uint u1 = xr[l + 32];
        const uint u2 = xr[l + 64];
        float s0 = wa * bf_lo(u0), s1 = wa * bf_hi(u0);
        s0 = fmaf(wb, bf_lo(u1), s0); s1 = fmaf(wb, bf_hi(u1), s1);
        s0 = fmaf(wc, bf_lo(u2), s0); s1 = fmaf(wc, bf_hi(u2), s1);
        s0 += __shfl_xor(s0, 16);   // merge complementary kbase (same pair p)
        s1 += __shfl_xor(s1, 16);
        const float val = kbase ? s1 : s0;
        const int ch = 2 * p + kbase;
        atomicAdd(&agg[(size_t)dst * CO + ch], val);
        if (l == 0) atomicAdd(&cnt[dst], 1.0f);
    }
}

// ---------------- kernel 3: out = agg/max(cnt,1) + x@root + bias ----------------
__global__ void out_kernel(const float* __restrict__ x, const float* __restrict__ root,
                           const float* __restrict__ bias, const float* __restrict__ cnt,
                           float* __restrict__ out, int N) {
    __shared__ float rs[CI * CO];  // 4 KiB
    __shared__ float bs[CO];
    for (int i = threadIdx.x; i < CI * CO; i += blockDim.x) rs[i] = root[i];
    if (threadIdx.x < CO) bs[threadIdx.x] = bias[threadIdx.x];
    __syncthreads();
    const int total = N * 8;  // channel quads
    for (int idx = blockIdx.x * blockDim.x + threadIdx.x; idx < total;
         idx += gridDim.x * blockDim.x) {
        const int n = idx >> 3;
        const int t = idx & 7;     // channels 4t..4t+3
        const float* xr = x + (size_t)n * CI;
        float a0 = 0.f, a1 = 0.f, a2 = 0.f, a3 = 0.f;
#pragma unroll
        for (int c = 0; c < CI; ++c) {
            const float4 rv = *(const float4*)&rs[c * CO + 4 * t];
            float xc = xr[c];
            a0 = fmaf(xc, rv.x, a0);
            a1 = fmaf(xc, rv.y, a1);
            a2 = fmaf(xc, rv.z, a2);
            a3 = fmaf(xc, rv.w, a3);
        }
        const float inv = 1.0f / fmaxf(cnt[n], 1.0f);
        float4 o = *(float4*)&out[(size_t)n * CO + 4 * t];
        const float4 bv = *(const float4*)&bs[4 * t];
        o.x = o.x * inv + a0 + bv.x;
        o.y = o.y * inv + a1 + bv.y;
        o.z = o.z * inv + a2 + bv.z;
        o.w = o.w * inv + a3 + bv.w;
        *(float4*)&out[(size_t)n * CO + 4 * t] = o;
    }
}

extern "C" void kernel_launch(void* const* d_in, const int* in_sizes, int n_in,
                              void* d_out, int out_size, void* d_ws, size_t ws_size,
                              hipStream_t stream) {
    const float* x      = (const float*)d_in[0];
    const int*   ei     = (const int*)d_in[1];
    const float* pseudo = (const float*)d_in[2];
    const float* g      = (const float*)d_in[3];
    const float* mu     = (const float*)d_in[4];
    const float* sigma  = (const float*)d_in[5];
    const float* root   = (const float*)d_in[6];
    const float* bias   = (const float*)d_in[7];
    float* out = (float*)d_out;

    const int N = in_sizes[0] / CI;
    const int E = in_sizes[1] / 2;

    uint*  xg = (uint*)d_ws;                          // N*96 uints = 62.9 MB
    uint4* W  = (uint4*)(xg + (size_t)N * QP);        // E*16B = 18.4 MB (16B-aligned)
    float* cnt = (float*)(W + E);                     // N floats

    hipMemsetAsync(d_out, 0, (size_t)out_size * sizeof(float), stream);
    hipMemsetAsync(cnt, 0, (size_t)N * sizeof(float), stream);

    const int blk = 256;

    gauss_kernel<<<(E + blk - 1) / blk, blk, 0, stream>>>(pseudo, mu, sigma, W, E);

    xg_kernel<<<2048, blk, 0, stream>>>(x, g, xg, N);

    const int gpb = blk / 32;
    int grid2 = (E + gpb - 1) / gpb;
    if (grid2 > 16384) grid2 = 16384;
    edge_kernel<<<grid2, blk, 0, stream>>>(ei, W, xg, out, cnt, E);

    int grid3 = (N * 8 + blk - 1) / blk;
    if (grid3 > 4096) grid3 = 4096;
    out_kernel<<<grid3, blk, 0, stream>>>(x, root, bias, cnt, out, N);
}